// Round 3
// baseline (1500.786 us; speedup 1.0000x reference)
//
#include <hip/hip_runtime.h>
#include <hip/hip_fp16.h>

#define N_NODES 200000
#define N_EDGES 12800000
#define DIM 10

// ---------------- full path (fp16 gather, NPB=256) ----------------
#define NPB 256
#define NB  782                       // ceil(200000/256)
#define CAP 17408                     // mean 16368, sd ~128 -> +8 sigma
#define P1_THREADS 1024
#define P1_EPT 16
#define P1_TILE (P1_THREADS * P1_EPT)
#define P2_THREADS 512
#define UNR 4
#define ROWH 12                       // padded halves per row (24B)

// ---------------- round-2 fallback path (f32 gather, NPB=512) ----------------
#define NPB5 512
#define NB5  391
#define CAP5 34816

__global__ __launch_bounds__(256) void conv16(const float* __restrict__ nf,
                                              __half* __restrict__ nf16) {
    int i = blockIdx.x * 256 + threadIdx.x;
    if (i >= N_NODES) return;
    const float2* __restrict__ r = reinterpret_cast<const float2*>(nf + (size_t)i * DIM);
    __half2 h[6];
    #pragma unroll
    for (int k = 0; k < 5; ++k) { float2 v = r[k]; h[k] = __floats2half2_rn(v.x, v.y); }
    h[5] = __floats2half2_rn(0.f, 0.f);
    uint2* __restrict__ w = reinterpret_cast<uint2*>(nf16 + (size_t)i * ROWH);
    w[0] = make_uint2(*(unsigned*)&h[0], *(unsigned*)&h[1]);
    w[1] = make_uint2(*(unsigned*)&h[2], *(unsigned*)&h[3]);
    w[2] = make_uint2(*(unsigned*)&h[4], *(unsigned*)&h[5]);
}

__global__ __launch_bounds__(P1_THREADS) void p1_bucket(
    const int* __restrict__ esrc, const int* __restrict__ edst,
    unsigned int* __restrict__ gcur, unsigned int* __restrict__ bbuf)
{
    __shared__ unsigned int hist[NB];
    __shared__ unsigned int base[NB];
    const int t = threadIdx.x;

    for (int b = t; b < NB; b += P1_THREADS) hist[b] = 0u;
    __syncthreads();

    const long tile0 = (long)blockIdx.x * P1_TILE;
    int          bkt[P1_EPT];
    unsigned int pkd[P1_EPT];

    #pragma unroll
    for (int k = 0; k < P1_EPT; ++k) {
        long e = tile0 + t + (long)k * P1_THREADS;
        if (e < N_EDGES) {
            int s = __builtin_nontemporal_load(&esrc[e]);
            int d = __builtin_nontemporal_load(&edst[e]);
            int b = d >> 8;                              // bucket of 256
            bkt[k] = b;
            pkd[k] = (unsigned int)s | ((unsigned int)(d & (NPB - 1)) << 18);
            atomicAdd(&hist[b], 1u);
        } else bkt[k] = -1;
    }
    __syncthreads();

    for (int b = t; b < NB; b += P1_THREADS) {
        unsigned int h = hist[b];
        if (h) base[b] = atomicAdd(&gcur[b], h);
        hist[b] = 0u;
    }
    __syncthreads();

    #pragma unroll
    for (int k = 0; k < P1_EPT; ++k) {
        int b = bkt[k];
        if (b < 0) continue;
        unsigned int r = atomicAdd(&hist[b], 1u);
        unsigned int pos = base[b] + r;
        if (pos < CAP)
            __builtin_nontemporal_store(pkd[k], &bbuf[(size_t)b * CAP + pos]);
    }
}

__device__ __forceinline__ void add_row_f16(float* a, uint2 q0, uint2 q1, uint2 q2) {
    float2 f;
    f = __half22float2(*(__half2*)&q0.x); atomicAdd(a + 0, f.x); atomicAdd(a + 1, f.y);
    f = __half22float2(*(__half2*)&q0.y); atomicAdd(a + 2, f.x); atomicAdd(a + 3, f.y);
    f = __half22float2(*(__half2*)&q1.x); atomicAdd(a + 4, f.x); atomicAdd(a + 5, f.y);
    f = __half22float2(*(__half2*)&q1.y); atomicAdd(a + 6, f.x); atomicAdd(a + 7, f.y);
    f = __half22float2(*(__half2*)&q2.x); atomicAdd(a + 8, f.x); atomicAdd(a + 9, f.y);
    atomicAdd(a + DIM, 1.0f);
}

__global__ __launch_bounds__(P2_THREADS) void p2_accum(
    const __half* __restrict__ nf16, const unsigned int* __restrict__ gcur,
    const unsigned int* __restrict__ bbuf, const float* __restrict__ W,
    const float* __restrict__ Bm, float* __restrict__ out)
{
    __shared__ float acc[NPB][DIM + 1];
    __shared__ float wsb[DIM * DIM];
    const int t = threadIdx.x;
    const int b = blockIdx.x;

    for (int i = t; i < NPB * (DIM + 1); i += P2_THREADS) (&acc[0][0])[i] = 0.f;
    if (t < DIM * DIM) wsb[t] = W[t] + Bm[t];
    __syncthreads();

    const int nseg = min((int)gcur[b], CAP);
    const unsigned int* __restrict__ seg = bbuf + (size_t)b * CAP;

    const int step = P2_THREADS * UNR;
    const int nmain = (nseg / step) * step;

    for (int i0 = 0; i0 < nmain; i0 += step) {
        unsigned int p[UNR];
        #pragma unroll
        for (int u = 0; u < UNR; ++u)
            p[u] = __builtin_nontemporal_load(&seg[i0 + u * P2_THREADS + t]);
        uint2 q[UNR][3];
        #pragma unroll
        for (int u = 0; u < UNR; ++u) {
            const uint2* __restrict__ rp =
                reinterpret_cast<const uint2*>(nf16 + (size_t)(p[u] & 0x3FFFFu) * ROWH);
            q[u][0] = rp[0]; q[u][1] = rp[1]; q[u][2] = rp[2];
        }
        #pragma unroll
        for (int u = 0; u < UNR; ++u)
            add_row_f16(acc[p[u] >> 18], q[u][0], q[u][1], q[u][2]);
    }
    for (int i = nmain + t; i < nseg; i += P2_THREADS) {
        unsigned int p = __builtin_nontemporal_load(&seg[i]);
        const uint2* __restrict__ rp =
            reinterpret_cast<const uint2*>(nf16 + (size_t)(p & 0x3FFFFu) * ROWH);
        add_row_f16(acc[p >> 18], rp[0], rp[1], rp[2]);
    }
    __syncthreads();

    if (t < NPB) {
        int node = b * NPB + t;
        if (node < N_NODES) {
            float inv = 1.0f / fmaxf(acc[t][DIM], 1.0f);
            float av[DIM], o[DIM];
            #pragma unroll
            for (int k = 0; k < DIM; ++k) av[k] = acc[t][k] * inv;
            #pragma unroll
            for (int j = 0; j < DIM; ++j) {
                float s = 0.f;
                #pragma unroll
                for (int k = 0; k < DIM; ++k) s = fmaf(av[k], wsb[j * DIM + k], s);
                o[j] = fmaxf(s, 0.f);
            }
            float2* __restrict__ orow = reinterpret_cast<float2*>(out + (size_t)node * DIM);
            #pragma unroll
            for (int k = 0; k < 5; ++k) orow[k] = make_float2(o[2 * k], o[2 * k + 1]);
        }
    }
}

// ======================= round-2 verified fallback =======================
__global__ __launch_bounds__(1024) void p1_bucket5(
    const int* __restrict__ esrc, const int* __restrict__ edst,
    unsigned int* __restrict__ gcur, unsigned int* __restrict__ bbuf)
{
    __shared__ unsigned int hist[NB5];
    __shared__ unsigned int base[NB5];
    const int t = threadIdx.x;
    for (int b = t; b < NB5; b += 1024) hist[b] = 0u;
    __syncthreads();
    const long tile0 = (long)blockIdx.x * P1_TILE;
    int bkt[P1_EPT]; unsigned int pkd[P1_EPT];
    #pragma unroll
    for (int k = 0; k < P1_EPT; ++k) {
        long e = tile0 + t + (long)k * 1024;
        if (e < N_EDGES) {
            int s = esrc[e]; int d = edst[e];
            int b = d >> 9; bkt[k] = b;
            pkd[k] = (unsigned int)s | ((unsigned int)(d & (NPB5 - 1)) << 18);
            atomicAdd(&hist[b], 1u);
        } else bkt[k] = -1;
    }
    __syncthreads();
    for (int b = t; b < NB5; b += 1024) {
        unsigned int h = hist[b];
        if (h) base[b] = atomicAdd(&gcur[b], h);
        hist[b] = 0u;
    }
    __syncthreads();
    #pragma unroll
    for (int k = 0; k < P1_EPT; ++k) {
        int b = bkt[k];
        if (b < 0) continue;
        unsigned int r = atomicAdd(&hist[b], 1u);
        unsigned int pos = base[b] + r;
        if (pos < CAP5) bbuf[(size_t)b * CAP5 + pos] = pkd[k];
    }
}

__global__ __launch_bounds__(1024) void p2_accum5(
    const float* __restrict__ nf, const unsigned int* __restrict__ gcur,
    const unsigned int* __restrict__ bbuf, const float* __restrict__ W,
    const float* __restrict__ Bm, float* __restrict__ out)
{
    __shared__ float acc[NPB5][DIM + 1];
    __shared__ float wsb[DIM * DIM];
    const int t = threadIdx.x;
    const int b = blockIdx.x;
    for (int i = t; i < NPB5 * (DIM + 1); i += 1024) (&acc[0][0])[i] = 0.f;
    if (t < DIM * DIM) wsb[t] = W[t] + Bm[t];
    __syncthreads();
    const int nseg = min((int)gcur[b], CAP5);
    const unsigned int* __restrict__ seg = bbuf + (size_t)b * CAP5;
    for (int i = t; i < nseg; i += 1024) {
        unsigned int p = seg[i];
        const float2* __restrict__ row =
            reinterpret_cast<const float2*>(nf + (size_t)(p & 0x3FFFFu) * DIM);
        float* a = acc[p >> 18];
        #pragma unroll
        for (int k = 0; k < 5; ++k) {
            float2 v = row[k];
            atomicAdd(a + 2 * k, v.x); atomicAdd(a + 2 * k + 1, v.y);
        }
        atomicAdd(a + DIM, 1.0f);
    }
    __syncthreads();
    for (int j = t; j < NPB5; j += 1024) {
        int node = b * NPB5 + j;
        if (node >= N_NODES) continue;
        float inv = 1.0f / fmaxf(acc[j][DIM], 1.0f);
        float av[DIM], o[DIM];
        #pragma unroll
        for (int k = 0; k < DIM; ++k) av[k] = acc[j][k] * inv;
        #pragma unroll
        for (int jj = 0; jj < DIM; ++jj) {
            float s = 0.f;
            #pragma unroll
            for (int k = 0; k < DIM; ++k) s = fmaf(av[k], wsb[jj * DIM + k], s);
            o[jj] = fmaxf(s, 0.f);
        }
        float2* __restrict__ orow = reinterpret_cast<float2*>(out + (size_t)node * DIM);
        #pragma unroll
        for (int k = 0; k < 5; ++k) orow[k] = make_float2(o[2 * k], o[2 * k + 1]);
    }
}

__global__ __launch_bounds__(256) void edge_scatter(
    const float* __restrict__ nf, const int* __restrict__ esrc,
    const int* __restrict__ edst, float* __restrict__ agg, float* __restrict__ cnt)
{
    int e = blockIdx.x * blockDim.x + threadIdx.x;
    if (e >= N_EDGES) return;
    int s = esrc[e]; int d = edst[e];
    const float2* __restrict__ row = reinterpret_cast<const float2*>(nf + (size_t)s * DIM);
    float* __restrict__ dstp = agg + (size_t)d * DIM;
    #pragma unroll
    for (int k = 0; k < 5; ++k) {
        float2 v = row[k];
        atomicAdd(dstp + 2 * k, v.x); atomicAdd(dstp + 2 * k + 1, v.y);
    }
    atomicAdd(cnt + d, 1.0f);
}

__global__ __launch_bounds__(256) void node_update(
    const float* __restrict__ agg, const float* __restrict__ cnt,
    const float* __restrict__ W, const float* __restrict__ B, float* __restrict__ out)
{
    __shared__ float ws[DIM * DIM];
    int t = threadIdx.x;
    if (t < DIM * DIM) ws[t] = W[t] + B[t];
    __syncthreads();
    int i = blockIdx.x * blockDim.x + t;
    if (i >= N_NODES) return;
    float inv = 1.0f / fmaxf(cnt[i], 1.0f);
    float a[DIM], o[DIM];
    const float2* __restrict__ arow = reinterpret_cast<const float2*>(agg + (size_t)i * DIM);
    #pragma unroll
    for (int k = 0; k < 5; ++k) {
        float2 v = arow[k];
        a[2 * k] = v.x * inv; a[2 * k + 1] = v.y * inv;
    }
    #pragma unroll
    for (int j = 0; j < DIM; ++j) {
        float s = 0.f;
        #pragma unroll
        for (int k = 0; k < DIM; ++k) s = fmaf(a[k], ws[j * DIM + k], s);
        o[j] = fmaxf(s, 0.f);
    }
    float2* __restrict__ orow = reinterpret_cast<float2*>(out + (size_t)i * DIM);
    #pragma unroll
    for (int k = 0; k < 5; ++k) orow[k] = make_float2(o[2 * k], o[2 * k + 1]);
}

extern "C" void kernel_launch(void* const* d_in, const int* in_sizes, int n_in,
                              void* d_out, int out_size, void* d_ws, size_t ws_size,
                              hipStream_t stream) {
    const float* nf   = (const float*)d_in[0];
    const float* W    = (const float*)d_in[1];
    const float* B    = (const float*)d_in[2];
    const int*   esrc = (const int*)d_in[3];
    const int*   edst = (const int*)d_in[4];
    float* out = (float*)d_out;

    // full path layout: [gcur pad 1024 u32][bbuf NB*CAP u32][nf16 N*12 halves]
    const size_t bbuf_off  = 1024;
    const size_t nf16_off  = bbuf_off + (size_t)NB * CAP;            // u32 units
    const size_t need_full = nf16_off * 4 + (size_t)N_NODES * ROWH * 2;
    const size_t need_r2   = (512 + (size_t)NB5 * CAP5) * 4;

    if (ws_size >= need_full) {
        unsigned int* gcur = (unsigned int*)d_ws;
        unsigned int* bbuf = gcur + bbuf_off;
        __half*       nf16 = (__half*)(gcur + nf16_off);

        hipMemsetAsync(gcur, 0, NB * sizeof(unsigned int), stream);
        conv16<<<(N_NODES + 255) / 256, 256, 0, stream>>>(nf, nf16);
        p1_bucket<<<(N_EDGES + P1_TILE - 1) / P1_TILE, P1_THREADS, 0, stream>>>(
            esrc, edst, gcur, bbuf);
        p2_accum<<<NB, P2_THREADS, 0, stream>>>(nf16, gcur, bbuf, W, B, out);
    } else if (ws_size >= need_r2) {
        unsigned int* gcur = (unsigned int*)d_ws;
        unsigned int* bbuf = gcur + 512;
        hipMemsetAsync(gcur, 0, NB5 * sizeof(unsigned int), stream);
        p1_bucket5<<<(N_EDGES + P1_TILE - 1) / P1_TILE, 1024, 0, stream>>>(
            esrc, edst, gcur, bbuf);
        p2_accum5<<<NB5, 1024, 0, stream>>>(nf, gcur, bbuf, W, B, out);
    } else {
        float* agg = (float*)d_ws;
        float* cnt = agg + (size_t)N_NODES * DIM;
        hipMemsetAsync(d_ws, 0, (size_t)(N_NODES * DIM + N_NODES) * sizeof(float), stream);
        edge_scatter<<<(N_EDGES + 255) / 256, 256, 0, stream>>>(nf, esrc, edst, agg, cnt);
        node_update<<<(N_NODES + 255) / 256, 256, 0, stream>>>(agg, cnt, W, B, out);
    }
}

// Round 4
// 1046.805 us; speedup vs baseline: 1.4337x; 1.4337x over previous
//
#include <hip/hip_runtime.h>
#include <hip/hip_fp16.h>

#define N_NODES 200000
#define N_EDGES 12800000
#define DIM 10

// ---------------- full path (split fp16 gather, NPB=256) ----------------
#define NPB 256
#define NB  782                       // ceil(200000/256)
#define CAP 17408                     // mean 16368, sd ~128 -> +8 sigma, pos<CAP guard
#define P1_THREADS 1024
#define P1_EPT 16
#define P1_TILE (P1_THREADS * P1_EPT)
#define P2_THREADS 512
#define UNR 8

// ---------------- round-2 fallback path (f32 gather, NPB=512) ----------------
#define NPB5 512
#define NB5  391
#define CAP5 34816

// Split feature layout: X[node] = dims 0..7 as 8 x fp16 (16 B, one dwordx4);
// Y[node] = dims 8..9 as 2 x fp16 (4 B). Combined 4.0 MB -> per-XCD L2 resident.
__global__ __launch_bounds__(256) void conv16s(const float* __restrict__ nf,
                                               uint4* __restrict__ X,
                                               unsigned* __restrict__ Y) {
    int i = blockIdx.x * 256 + threadIdx.x;
    if (i >= N_NODES) return;
    const float2* __restrict__ r = reinterpret_cast<const float2*>(nf + (size_t)i * DIM);
    __half2 h[5];
    #pragma unroll
    for (int k = 0; k < 5; ++k) { float2 v = r[k]; h[k] = __floats2half2_rn(v.x, v.y); }
    X[i] = make_uint4(*(unsigned*)&h[0], *(unsigned*)&h[1],
                      *(unsigned*)&h[2], *(unsigned*)&h[3]);
    Y[i] = *(unsigned*)&h[4];
}

__global__ __launch_bounds__(P1_THREADS) void p1_bucket(
    const int* __restrict__ esrc, const int* __restrict__ edst,
    unsigned int* __restrict__ gcur, unsigned int* __restrict__ bbuf)
{
    __shared__ unsigned int hist[NB];
    __shared__ unsigned int base[NB];
    const int t = threadIdx.x;

    for (int b = t; b < NB; b += P1_THREADS) hist[b] = 0u;
    __syncthreads();

    const long tile0 = (long)blockIdx.x * P1_TILE;
    int          bkt[P1_EPT];
    unsigned int pkd[P1_EPT];

    #pragma unroll
    for (int k = 0; k < P1_EPT; ++k) {
        long e = tile0 + t + (long)k * P1_THREADS;
        if (e < N_EDGES) {
            int s = esrc[e];
            int d = edst[e];
            int b = d >> 8;
            bkt[k] = b;
            pkd[k] = (unsigned int)s | ((unsigned int)(d & (NPB - 1)) << 18);
            atomicAdd(&hist[b], 1u);
        } else bkt[k] = -1;
    }
    __syncthreads();

    for (int b = t; b < NB; b += P1_THREADS) {
        unsigned int h = hist[b];
        if (h) base[b] = atomicAdd(&gcur[b], h);
        hist[b] = 0u;
    }
    __syncthreads();

    #pragma unroll
    for (int k = 0; k < P1_EPT; ++k) {
        int b = bkt[k];
        if (b < 0) continue;
        unsigned int r = atomicAdd(&hist[b], 1u);
        unsigned int pos = base[b] + r;
        if (pos < CAP)
            bbuf[(size_t)b * CAP + pos] = pkd[k];
    }
}

__device__ __forceinline__ void add_row_split(float* __restrict__ a, uint4 qx, unsigned qy) {
    float2 f;
    f = __half22float2(*(__half2*)&qx.x); atomicAdd(a + 0, f.x); atomicAdd(a + 1, f.y);
    f = __half22float2(*(__half2*)&qx.y); atomicAdd(a + 2, f.x); atomicAdd(a + 3, f.y);
    f = __half22float2(*(__half2*)&qx.z); atomicAdd(a + 4, f.x); atomicAdd(a + 5, f.y);
    f = __half22float2(*(__half2*)&qx.w); atomicAdd(a + 6, f.x); atomicAdd(a + 7, f.y);
    f = __half22float2(*(__half2*)&qy);   atomicAdd(a + 8, f.x); atomicAdd(a + 9, f.y);
    atomicAdd(a + DIM, 1.0f);
}

__global__ __launch_bounds__(P2_THREADS) void p2_accum(
    const uint4* __restrict__ X, const unsigned* __restrict__ Y,
    const unsigned int* __restrict__ gcur, const unsigned int* __restrict__ bbuf,
    const float* __restrict__ W, const float* __restrict__ Bm,
    float* __restrict__ out)
{
    __shared__ float acc[NPB][DIM + 1];   // stride 11 floats: coprime with 32 banks
    __shared__ float wsb[DIM * DIM];
    const int t = threadIdx.x;
    const int b = blockIdx.x;

    for (int i = t; i < NPB * (DIM + 1); i += P2_THREADS) (&acc[0][0])[i] = 0.f;
    if (t < DIM * DIM) wsb[t] = W[t] + Bm[t];
    __syncthreads();

    const int nseg = min((int)gcur[b], CAP);
    const unsigned int* __restrict__ seg = bbuf + (size_t)b * CAP;
    const int step = P2_THREADS * UNR;

    for (int i0 = 0; i0 < nseg; i0 += step) {
        unsigned int p[UNR];
        bool         ok[UNR];
        // --- issue phase: all seg loads, then all gathers ---
        #pragma unroll
        for (int u = 0; u < UNR; ++u) {
            int i = i0 + u * P2_THREADS + t;
            ok[u] = (i < nseg);
            p[u] = __builtin_nontemporal_load(&seg[ok[u] ? i : 0]);
        }
        uint4    qx[UNR];
        unsigned qy[UNR];
        #pragma unroll
        for (int u = 0; u < UNR; ++u) {
            unsigned src = p[u] & 0x3FFFFu;
            qx[u] = X[src];
            qy[u] = Y[src];
        }
        // pin the schedule: all gathers issued before any LDS consume
        asm volatile("" ::: "memory");
        // --- consume phase ---
        #pragma unroll
        for (int u = 0; u < UNR; ++u)
            if (ok[u]) add_row_split(acc[p[u] >> 18], qx[u], qy[u]);
    }
    __syncthreads();

    if (t < NPB) {
        int node = b * NPB + t;
        if (node < N_NODES) {
            float inv = 1.0f / fmaxf(acc[t][DIM], 1.0f);
            float av[DIM], o[DIM];
            #pragma unroll
            for (int k = 0; k < DIM; ++k) av[k] = acc[t][k] * inv;
            #pragma unroll
            for (int j = 0; j < DIM; ++j) {
                float s = 0.f;
                #pragma unroll
                for (int k = 0; k < DIM; ++k) s = fmaf(av[k], wsb[j * DIM + k], s);
                o[j] = fmaxf(s, 0.f);
            }
            float2* __restrict__ orow = reinterpret_cast<float2*>(out + (size_t)node * DIM);
            #pragma unroll
            for (int k = 0; k < 5; ++k) orow[k] = make_float2(o[2 * k], o[2 * k + 1]);
        }
    }
}

// ======================= round-2 verified fallback =======================
__global__ __launch_bounds__(1024) void p1_bucket5(
    const int* __restrict__ esrc, const int* __restrict__ edst,
    unsigned int* __restrict__ gcur, unsigned int* __restrict__ bbuf)
{
    __shared__ unsigned int hist[NB5];
    __shared__ unsigned int base[NB5];
    const int t = threadIdx.x;
    for (int b = t; b < NB5; b += 1024) hist[b] = 0u;
    __syncthreads();
    const long tile0 = (long)blockIdx.x * P1_TILE;
    int bkt[P1_EPT]; unsigned int pkd[P1_EPT];
    #pragma unroll
    for (int k = 0; k < P1_EPT; ++k) {
        long e = tile0 + t + (long)k * 1024;
        if (e < N_EDGES) {
            int s = esrc[e]; int d = edst[e];
            int b = d >> 9; bkt[k] = b;
            pkd[k] = (unsigned int)s | ((unsigned int)(d & (NPB5 - 1)) << 18);
            atomicAdd(&hist[b], 1u);
        } else bkt[k] = -1;
    }
    __syncthreads();
    for (int b = t; b < NB5; b += 1024) {
        unsigned int h = hist[b];
        if (h) base[b] = atomicAdd(&gcur[b], h);
        hist[b] = 0u;
    }
    __syncthreads();
    #pragma unroll
    for (int k = 0; k < P1_EPT; ++k) {
        int b = bkt[k];
        if (b < 0) continue;
        unsigned int r = atomicAdd(&hist[b], 1u);
        unsigned int pos = base[b] + r;
        if (pos < CAP5) bbuf[(size_t)b * CAP5 + pos] = pkd[k];
    }
}

__global__ __launch_bounds__(1024) void p2_accum5(
    const float* __restrict__ nf, const unsigned int* __restrict__ gcur,
    const unsigned int* __restrict__ bbuf, const float* __restrict__ W,
    const float* __restrict__ Bm, float* __restrict__ out)
{
    __shared__ float acc[NPB5][DIM + 1];
    __shared__ float wsb[DIM * DIM];
    const int t = threadIdx.x;
    const int b = blockIdx.x;
    for (int i = t; i < NPB5 * (DIM + 1); i += 1024) (&acc[0][0])[i] = 0.f;
    if (t < DIM * DIM) wsb[t] = W[t] + Bm[t];
    __syncthreads();
    const int nseg = min((int)gcur[b], CAP5);
    const unsigned int* __restrict__ seg = bbuf + (size_t)b * CAP5;
    for (int i = t; i < nseg; i += 1024) {
        unsigned int p = seg[i];
        const float2* __restrict__ row =
            reinterpret_cast<const float2*>(nf + (size_t)(p & 0x3FFFFu) * DIM);
        float* a = acc[p >> 18];
        #pragma unroll
        for (int k = 0; k < 5; ++k) {
            float2 v = row[k];
            atomicAdd(a + 2 * k, v.x); atomicAdd(a + 2 * k + 1, v.y);
        }
        atomicAdd(a + DIM, 1.0f);
    }
    __syncthreads();
    for (int j = t; j < NPB5; j += 1024) {
        int node = b * NPB5 + j;
        if (node >= N_NODES) continue;
        float inv = 1.0f / fmaxf(acc[j][DIM], 1.0f);
        float av[DIM], o[DIM];
        #pragma unroll
        for (int k = 0; k < DIM; ++k) av[k] = acc[j][k] * inv;
        #pragma unroll
        for (int jj = 0; jj < DIM; ++jj) {
            float s = 0.f;
            #pragma unroll
            for (int k = 0; k < DIM; ++k) s = fmaf(av[k], wsb[jj * DIM + k], s);
            o[jj] = fmaxf(s, 0.f);
        }
        float2* __restrict__ orow = reinterpret_cast<float2*>(out + (size_t)node * DIM);
        #pragma unroll
        for (int k = 0; k < 5; ++k) orow[k] = make_float2(o[2 * k], o[2 * k + 1]);
    }
}

__global__ __launch_bounds__(256) void edge_scatter(
    const float* __restrict__ nf, const int* __restrict__ esrc,
    const int* __restrict__ edst, float* __restrict__ agg, float* __restrict__ cnt)
{
    int e = blockIdx.x * blockDim.x + threadIdx.x;
    if (e >= N_EDGES) return;
    int s = esrc[e]; int d = edst[e];
    const float2* __restrict__ row = reinterpret_cast<const float2*>(nf + (size_t)s * DIM);
    float* __restrict__ dstp = agg + (size_t)d * DIM;
    #pragma unroll
    for (int k = 0; k < 5; ++k) {
        float2 v = row[k];
        atomicAdd(dstp + 2 * k, v.x); atomicAdd(dstp + 2 * k + 1, v.y);
    }
    atomicAdd(cnt + d, 1.0f);
}

__global__ __launch_bounds__(256) void node_update(
    const float* __restrict__ agg, const float* __restrict__ cnt,
    const float* __restrict__ W, const float* __restrict__ B, float* __restrict__ out)
{
    __shared__ float ws[DIM * DIM];
    int t = threadIdx.x;
    if (t < DIM * DIM) ws[t] = W[t] + B[t];
    __syncthreads();
    int i = blockIdx.x * blockDim.x + t;
    if (i >= N_NODES) return;
    float inv = 1.0f / fmaxf(cnt[i], 1.0f);
    float a[DIM], o[DIM];
    const float2* __restrict__ arow = reinterpret_cast<const float2*>(agg + (size_t)i * DIM);
    #pragma unroll
    for (int k = 0; k < 5; ++k) {
        float2 v = arow[k];
        a[2 * k] = v.x * inv; a[2 * k + 1] = v.y * inv;
    }
    #pragma unroll
    for (int j = 0; j < DIM; ++j) {
        float s = 0.f;
        #pragma unroll
        for (int k = 0; k < DIM; ++k) s = fmaf(a[k], ws[j * DIM + k], s);
        o[j] = fmaxf(s, 0.f);
    }
    float2* __restrict__ orow = reinterpret_cast<float2*>(out + (size_t)i * DIM);
    #pragma unroll
    for (int k = 0; k < 5; ++k) orow[k] = make_float2(o[2 * k], o[2 * k + 1]);
}

extern "C" void kernel_launch(void* const* d_in, const int* in_sizes, int n_in,
                              void* d_out, int out_size, void* d_ws, size_t ws_size,
                              hipStream_t stream) {
    const float* nf   = (const float*)d_in[0];
    const float* W    = (const float*)d_in[1];
    const float* B    = (const float*)d_in[2];
    const int*   esrc = (const int*)d_in[3];
    const int*   edst = (const int*)d_in[4];
    float* out = (float*)d_out;

    // full path layout (u32 units): [gcur 1024][bbuf NB*CAP][X N*4][Y N]
    const size_t bbuf_off  = 1024;
    const size_t x_off     = bbuf_off + (size_t)NB * CAP;
    const size_t y_off     = x_off + (size_t)N_NODES * 4;
    const size_t need_full = (y_off + (size_t)N_NODES) * 4;           // ~58.5 MB
    const size_t need_r2   = (512 + (size_t)NB5 * CAP5) * 4;          // ~54.5 MB

    if (ws_size >= need_full) {
        unsigned int* gcur = (unsigned int*)d_ws;
        unsigned int* bbuf = gcur + bbuf_off;
        uint4*        X    = (uint4*)(gcur + x_off);
        unsigned*     Y    = gcur + y_off;

        hipMemsetAsync(gcur, 0, NB * sizeof(unsigned int), stream);
        conv16s<<<(N_NODES + 255) / 256, 256, 0, stream>>>(nf, X, Y);
        p1_bucket<<<(N_EDGES + P1_TILE - 1) / P1_TILE, P1_THREADS, 0, stream>>>(
            esrc, edst, gcur, bbuf);
        p2_accum<<<NB, P2_THREADS, 0, stream>>>(X, Y, gcur, bbuf, W, B, out);
    } else if (ws_size >= need_r2) {
        unsigned int* gcur = (unsigned int*)d_ws;
        unsigned int* bbuf = gcur + 512;
        hipMemsetAsync(gcur, 0, NB5 * sizeof(unsigned int), stream);
        p1_bucket5<<<(N_EDGES + P1_TILE - 1) / P1_TILE, 1024, 0, stream>>>(
            esrc, edst, gcur, bbuf);
        p2_accum5<<<NB5, 1024, 0, stream>>>(nf, gcur, bbuf, W, B, out);
    } else {
        float* agg = (float*)d_ws;
        float* cnt = agg + (size_t)N_NODES * DIM;
        hipMemsetAsync(d_ws, 0, (size_t)(N_NODES * DIM + N_NODES) * sizeof(float), stream);
        edge_scatter<<<(N_EDGES + 255) / 256, 256, 0, stream>>>(nf, esrc, edst, agg, cnt);
        node_update<<<(N_NODES + 255) / 256, 256, 0, stream>>>(agg, cnt, W, B, out);
    }
}